// Round 14
// baseline (277.221 us; speedup 1.0000x reference)
//
#include <hip/hip_runtime.h>

#define DD 384
#define NB 64
#define NATOM 8192
#define RB 394              // row buckets: icy+5, icy in [-5,388]
#define CB 51               // col buckets: (icx+16)>>3, icx in [-5,388] -> [1,50]
#define NBKT (RB * CB)      // 20094
#define OFFSTRIDE (NBKT + 4)
#define NCH 4               // scan chunks per image
#define CHSZ 5120           // buckets per chunk (4*5120 = 20480 >= NBKT)

typedef short short8 __attribute__((ext_vector_type(8)));
typedef float f32x4 __attribute__((ext_vector_type(4)));
typedef unsigned u32x4 __attribute__((ext_vector_type(4)));

// float -> bf16 (RNE) as ushort
__device__ inline unsigned bf1(float a) {
    unsigned u = __float_as_uint(a);
    return (u + 0x7FFFu + ((u >> 16) & 1u)) >> 16;
}
__device__ inline unsigned bfpack(float a, float b) {
    return bf1(a) | (bf1(b) << 16);
}

// Pose one atom -> (X, Y) in physical coords.
__device__ inline float2 pose_one(const float* __restrict__ crd,
                                  const float* __restrict__ rot,
                                  const float* __restrict__ rot_init,
                                  const float* __restrict__ trans, int idx) {
    int b = idx >> 13;
    const float* p = crd + (long)idx * 3;
    float x0 = p[0], y0 = p[1], z0 = p[2];
    float q0 = x0 * rot_init[0] + y0 * rot_init[3] + z0 * rot_init[6] + trans[0];
    float q1 = x0 * rot_init[1] + y0 * rot_init[4] + z0 * rot_init[7] + trans[1];
    float q2 = x0 * rot_init[2] + y0 * rot_init[5] + z0 * rot_init[8] + trans[2];
    const float* R = rot + b * 9;
    float2 o;
    o.x = q0 * R[0] + q1 * R[1] + q2 * R[2];
    o.y = q0 * R[3] + q1 * R[4] + q2 * R[5];
    return o;
}

// ---------------------------------------------------------------------------
// Bucketing (R13 structure, verified 254us): count (+ pose cache) ->
// two-kernel parallel scan -> scatter. Unchanged this round.
// ---------------------------------------------------------------------------
__global__ void count_atoms(const float* __restrict__ crd,
                            const float* __restrict__ rot,
                            const float* __restrict__ rot_init,
                            const float* __restrict__ trans,
                            int* __restrict__ counts,
                            float2* __restrict__ posed) {
    int idx = blockIdx.x * 256 + threadIdx.x;
    float2 v = pose_one(crd, rot, rot_init, trans, idx);
    posed[idx] = v;
    int icx = (int)rintf(v.x + 192.0f);
    int icy = (int)rintf(v.y + 192.0f);
    if (icx < -5 || icx > 388 || icy < -5 || icy > 388) return;
    int bi = (icy + 5) * CB + ((icx + 16) >> 3);
    atomicAdd(&counts[(idx >> 13) * NBKT + bi], 1);
}

// scan_a: one block per (image, chunk); local exclusive scan of 5120 buckets
// (5 coalesced 1024-tiles), zeroes cnt (scatter cursors), emits chunk total.
__global__ __launch_bounds__(1024) void scan_a(int* __restrict__ counts,
                                               int* __restrict__ offs,
                                               int* __restrict__ chunktot) {
    int bc = blockIdx.x;                 // image*NCH + chunk
    int b = bc >> 2, ch = bc & 3;
    int base = ch * CHSZ;
    int t = threadIdx.x, lane = t & 63, wid = t >> 6;
    int* cnt = counts + b * NBKT;
    int* off = offs + b * OFFSTRIDE;
    __shared__ int wsum[16];
    __shared__ int carrySm;
    if (t == 0) carrySm = 0;
    __syncthreads();
    for (int tile = 0; tile < 5; ++tile) {
        int k = base + tile * 1024 + t;
        int v = (k < NBKT) ? cnt[k] : 0;  // coalesced
        int incl = v;
#pragma unroll
        for (int d = 1; d < 64; d <<= 1) {
            int u = __shfl_up(incl, d);
            if (lane >= d) incl += u;
        }
        if (lane == 63) wsum[wid] = incl;
        __syncthreads();
        if (wid == 0) {
            int s = (lane < 16) ? wsum[lane] : 0;
            int si = s;
#pragma unroll
            for (int d = 1; d < 16; d <<= 1) {
                int u = __shfl_up(si, d);
                if (lane >= d) si += u;
            }
            if (lane < 16) wsum[lane] = si - s;  // exclusive
        }
        __syncthreads();
        int excl = incl - v + wsum[wid] + carrySm;
        if (k < NBKT) {
            off[k] = excl;               // chunk-local exclusive scan
            cnt[k] = 0;                  // reuse as scatter cursor
        }
        __syncthreads();                 // reads of carrySm done before bump
        if (t == 1023) carrySm = excl + v;  // = carry_in + tile total
        __syncthreads();
    }
    if (t == 0) chunktot[bc] = carrySm;  // chunk total
}

// scan_b: one block per (image, chunk); adds the sum of preceding chunks'
// totals to this chunk's entries. Chunk-0 blocks write off[NBKT] = total.
__global__ __launch_bounds__(1024) void scan_b(int* __restrict__ offs,
                                               const int* __restrict__ chunktot) {
    int bc = blockIdx.x;
    int b = bc >> 2, ch = bc & 3;
    const int* ct = chunktot + b * NCH;
    int* off = offs + b * OFFSTRIDE;
    int t = threadIdx.x;
    if (ch == 0) {
        if (t == 0) off[NBKT] = ct[0] + ct[1] + ct[2] + ct[3];
        return;
    }
    int basev = 0;
    for (int i = 0; i < ch; i++) basev += ct[i];
    int k0 = ch * CHSZ;
    for (int tile = 0; tile < 5; ++tile) {
        int k = k0 + tile * 1024 + t;
        if (k < NBKT) off[k] += basev;   // coalesced RMW
    }
}

__global__ void scatter_atoms(const float2* __restrict__ posed,
                              int* __restrict__ cursors,
                              const int* __restrict__ offs,
                              float2* __restrict__ sorted) {
    int idx = blockIdx.x * 256 + threadIdx.x;
    float2 v = posed[idx];               // coalesced 8B re-read (same bits)
    int icx = (int)rintf(v.x + 192.0f);
    int icy = (int)rintf(v.y + 192.0f);
    if (icx < -5 || icx > 388 || icy < -5 || icy > 388) return;
    int b = idx >> 13;
    int bi = (icy + 5) * CB + ((icx + 16) >> 3);
    int pos = offs[b * OFFSTRIDE + bi] + atomicAdd(&cursors[b * NBKT + bi], 1);
    sorted[(long)b * NATOM + pos] = v;
}

// ---------------------------------------------------------------------------
// MFMA splat, 32x32-tile-per-wave (R14). R13 PMC: 57us, VALUBusy 67% but
// MfmaUtil 0.8% -- per-wave fixed costs (prefix-scan, copy loop, prologue)
// dominated the ~9us chunk-body arithmetic. Amortize: one wave owns a 32x32
// tile = 4 16x16 MFMA accumulators acc[ry][rx]; per 32-atom chunk, 2 ey
// row-set fragments (rows +0/+16) x 2 ex col-set fragments (cols +0/+16)
// feed 4 MFMAs. Waves drop 4x (36864->9216), atom replication drops 1.53x
// (window 42x42 per 1024px vs 26x26 per 256px), copy volume -1.53x. The
// gather machinery (fine row buckets + LDS compaction) is unchanged -- R12
// proved it pays for itself vs masked direct reads. All exp/mask/pack ops
// bit-identical to the verified R13 body.
// ---------------------------------------------------------------------------
#define LCAP 768
#define LSZ  800   // LCAP + 32 pad slots

__global__ __launch_bounds__(256) void splat_mfma(const float2* __restrict__ sorted,
                                                  const int* __restrict__ offs,
                                                  float* __restrict__ img,
                                                  unsigned short* __restrict__ img_bf) {
    __shared__ __align__(16) float2 list[4][LSZ];
    int b = blockIdx.z;
    int wv = __builtin_amdgcn_readfirstlane((int)(threadIdx.x >> 6));
    int lane = threadIdx.x & 63;
    int tx = blockIdx.x * 4 + wv;      // 0..11
    int ty = blockIdx.y;               // 0..11
    int c0 = tx * 32, r0 = ty * 32;

    const int* off = offs + b * OFFSTRIDE;
    const float2* srt = sorted + (long)b * NATOM;

    int cb_lo = (c0 + 11) >> 3;          // icx >= c0-5 (8px col buckets)
    int cb_end = ((c0 + 52) >> 3) + 1;   // icx <= c0+36, end-exclusive
    // rows: icy in [r0-5, r0+36] -> rb = icy+5 in [r0, r0+41]: 42 buckets

    int cur = 0, iend = 0;
    if (lane < 42) {                     // one lane per row-bucket
        int rb = r0 + lane;
        cur = off[rb * CB + cb_lo];
        iend = off[rb * CB + cb_end];
    }

    f32x4 acc00 = {0.f, 0.f, 0.f, 0.f}, acc01 = {0.f, 0.f, 0.f, 0.f};
    f32x4 acc10 = {0.f, 0.f, 0.f, 0.f}, acc11 = {0.f, 0.f, 0.f, 0.f};
    int m = lane & 15;
    float rowf0 = (float)(r0 + m), rowf1 = rowf0 + 16.0f;
    float colf0 = (float)(c0 + m), colf1 = colf0 + 16.0f;
    float py0 = rowf0 - 192.0f, py1 = py0 + 16.0f;
    float px0 = colf0 - 192.0f, px1 = px0 + 16.0f;
    int g8 = (lane >> 4) << 3;           // k-slice base within chunk
    const float kneg = -0.32059868f;     // -(1/4.5)*log2(e)
    float2* wl = list[wv];

    for (int round = 0; round < 24; ++round) {
        int len = (lane < 42) ? (iend - cur) : 0;
        int incl = len;                  // exclusive scan via shfl_up
#pragma unroll
        for (int d = 1; d < 64; d <<= 1) {
            int t = __shfl_up(incl, d);
            if (lane >= d) incl += t;
        }
        int excl = incl - len;
        int totrem = __builtin_amdgcn_readfirstlane(__shfl(incl, 63));
        if (totrem == 0) break;
        int total = min(totrem, LCAP);
        int cnt = min(len, max(0, LCAP - excl));
        for (int j = 0; j < cnt; j++) wl[excl + j] = srt[cur + j];
        cur += cnt;
        int padn = (32 - (total & 31)) & 31;
        if (lane < padn) wl[total + lane] = (float2){3.0e5f, 3.0e5f};
        asm volatile("s_waitcnt lgkmcnt(0)" ::: "memory");  // wave-local LDS fence
        __builtin_amdgcn_sched_barrier(0);                  // no hoist past fence

        int nch = (total + 31) >> 5;
        for (int ch = 0; ch < nch; ch++) {
            const f32x4* qp = (const f32x4*)&wl[ch * 32 + g8];  // 2 atoms per read
            u32x4 au0, au1, bu0, bu1;
#pragma unroll
            for (int p = 0; p < 4; p++) {
                f32x4 q = qp[p];         // (X0,Y0,X1,Y1); 16-lane broadcast
                float cy0 = rintf(q[1] + 192.0f), cy1 = rintf(q[3] + 192.0f);
                float cx0 = rintf(q[0] + 192.0f), cx1 = rintf(q[2] + 192.0f);
                // ey row-set 0 (rows r0+m)
                float d0 = py0 - q[1], d1 = py0 - q[3];
                float e00 = (fabsf(rowf0 - cy0) <= 5.0f) ? exp2f(d0 * d0 * kneg) : 0.0f;
                float e01 = (fabsf(rowf0 - cy1) <= 5.0f) ? exp2f(d1 * d1 * kneg) : 0.0f;
                au0[p] = bfpack(e00, e01);
                // ey row-set 1 (rows r0+16+m)
                float d2 = py1 - q[1], d3 = py1 - q[3];
                float e10 = (fabsf(rowf1 - cy0) <= 5.0f) ? exp2f(d2 * d2 * kneg) : 0.0f;
                float e11 = (fabsf(rowf1 - cy1) <= 5.0f) ? exp2f(d3 * d3 * kneg) : 0.0f;
                au1[p] = bfpack(e10, e11);
                // ex col-set 0 (cols c0+m)
                float f0 = px0 - q[0], f1 = px0 - q[2];
                float g00 = (fabsf(colf0 - cx0) <= 5.0f) ? exp2f(f0 * f0 * kneg) : 0.0f;
                float g01 = (fabsf(colf0 - cx1) <= 5.0f) ? exp2f(f1 * f1 * kneg) : 0.0f;
                bu0[p] = bfpack(g00, g01);
                // ex col-set 1 (cols c0+16+m)
                float f2 = px1 - q[0], f3 = px1 - q[2];
                float g10 = (fabsf(colf1 - cx0) <= 5.0f) ? exp2f(f2 * f2 * kneg) : 0.0f;
                float g11 = (fabsf(colf1 - cx1) <= 5.0f) ? exp2f(f3 * f3 * kneg) : 0.0f;
                bu1[p] = bfpack(g10, g11);
            }
            short8 a0 = __builtin_bit_cast(short8, au0);
            short8 a1 = __builtin_bit_cast(short8, au1);
            short8 b0 = __builtin_bit_cast(short8, bu0);
            short8 b1 = __builtin_bit_cast(short8, bu1);
            acc00 = __builtin_amdgcn_mfma_f32_16x16x32_bf16(a0, b0, acc00, 0, 0, 0);
            acc01 = __builtin_amdgcn_mfma_f32_16x16x32_bf16(a0, b1, acc01, 0, 0, 0);
            acc10 = __builtin_amdgcn_mfma_f32_16x16x32_bf16(a1, b0, acc10, 0, 0, 0);
            acc11 = __builtin_amdgcn_mfma_f32_16x16x32_bf16(a1, b1, acc11, 0, 0, 0);
        }
        if (totrem <= LCAP) break;       // everything consumed this round
    }

    // C layout per 16x16 quadrant: col = lane&15, row = (lane>>4)*4 + r
    int q4 = (lane >> 4) * 4;
#pragma unroll
    for (int r = 0; r < 4; r++) {
        long o00 = ((long)b * DD + r0 + q4 + r) * DD + c0 + m;
        long o01 = ((long)b * DD + r0 + q4 + r) * DD + c0 + 16 + m;
        long o10 = ((long)b * DD + r0 + 16 + q4 + r) * DD + c0 + m;
        long o11 = ((long)b * DD + r0 + 16 + q4 + r) * DD + c0 + 16 + m;
        img[o00] = acc00[r];  img_bf[o00] = (unsigned short)bf1(acc00[r]);
        img[o01] = acc01[r];  img_bf[o01] = (unsigned short)bf1(acc01[r]);
        img[o10] = acc10[r];  img_bf[o10] = (unsigned short)bf1(acc10[r]);
        img[o11] = acc11[r];  img_bf[o11] = (unsigned short)bf1(acc11[r]);
    }
}

// ---------------------------------------------------------------------------
// DFT-derived weights (bf16): Bt1 = [U; S] (768x384), Bt2 = [U|-2S] (384x768).
// y = U*Y*U - 2*S*Y*S == Re(f)-Im(f) of double-fftshifted FFT2.
// ---------------------------------------------------------------------------
__global__ void gen_w(unsigned short* __restrict__ Bt1,
                      unsigned short* __restrict__ Bt2) {
    int idx = blockIdx.x * 256 + threadIdx.x;
    if (idx >= DD * DD) return;
    int i = idx / DD, j = idx % DD;
    int t = (i - 192) * (j - 192);
    int r = t % DD;
    if (r < 0) r += DD;
    float th = (float)r * (6.28318530717958647692f / (float)DD);
    float s = sinf(th), c = cosf(th);
    Bt1[i * DD + j] = (unsigned short)bf1(c + s);
    Bt1[(DD + i) * DD + j] = (unsigned short)bf1(s);
    Bt2[i * 768 + j] = (unsigned short)bf1(c + s);
    Bt2[i * 768 + 384 + j] = (unsigned short)bf1(-2.0f * s);
}

// ---------------------------------------------------------------------------
// bf16 MFMA GEMM: C[row][col] = sum_k A[row][k] * B[col][k].
// A is the SHARED bf16 weight matrix (row stride K). B is BATCHED (stride sB).
// 1D grid + bijective XCD swizzle (R7: FETCH 117->27MB) + T2 LDS XOR swizzle
// (R9: bank-conflict 1.24e7 -> fixed, -40us). BFOLD: B is the folded view of
// stage-1's C' (768x384 bf16): B[i][k] = k<384 ? C'[i][k] : C'[384+i][k-384].
// ---------------------------------------------------------------------------
template <bool CBF16, bool BFOLD>
__global__ __launch_bounds__(256) void gemm_mfma(const unsigned short* __restrict__ Ag,
                                                 const unsigned short* __restrict__ Bg,
                                                 long sB,
                                                 void* __restrict__ Cg, long sC,
                                                 int K, int ldc, int nx, int bpi) {
    __shared__ uint4 lds4[2048];  // A: [0,1024), B: [1024,2048)

    int cpx = gridDim.x >> 3;                 // blocks per XCD chunk
    int wg = blockIdx.x;
    int lin = (wg & 7) * cpx + (wg >> 3);     // bijective XCD swizzle
    int bz = lin / bpi;
    int rr = lin - bz * bpi;
    int m0 = (rr / nx) * 128, n0 = (rr % nx) * 128;
    int tid = threadIdx.x;
    int lane = tid & 63, w = tid >> 6;
    int wm = w >> 1, wn = w & 1;

    f32x4 acc[4][4];
#pragma unroll
    for (int i = 0; i < 4; i++)
#pragma unroll
        for (int j = 0; j < 4; j++) acc[i][j] = (f32x4){0.f, 0.f, 0.f, 0.f};

    const unsigned short* Bh = Bg + (long)bz * sB;

    // read-side swizzled lane offset (same function of the logical index)
    int lsw = lane ^ (((lane >> 4) & 3) << 1);

    for (int k0 = 0; k0 < K; k0 += 64) {
        __syncthreads();
#pragma unroll
        for (int cc = 0; cc < 4; cc++) {
            int c = tid + cc * 256;
            int m = c >> 3, kc = (c & 7) << 3;
            int li = ((m >> 4) * 2 + (kc >> 5)) * 64 +
                     ((m & 15) | (((kc >> 3) & 3) << 4));
            li ^= ((kc >> 3) & 3) << 1;   // T2 swizzle (== ((li>>4)&3)<<1)
            // A tile (shared weights, always bf16, row stride K)
            lds4[li] = *(const uint4*)(Ag + (long)(m0 + m) * K + k0 + kc);
            // B tile (batched bf16)
            uint4 wv;
            if (BFOLD) {
                int kk = k0 + kc;  // 16B run stays within one 384-half (64|384)
                long boff = (kk >= 384)
                                ? ((long)(384 + n0 + m) * 384 + (kk - 384))
                                : ((long)(n0 + m) * 384 + kk);
                wv = *(const uint4*)(Bh + boff);
            } else {
                wv = *(const uint4*)(Bh + (long)(n0 + m) * K + k0 + kc);
            }
            lds4[1024 + li] = wv;
        }
        __syncthreads();
#pragma unroll
        for (int ki = 0; ki < 2; ki++) {
            short8 a[4], bfr[4];
#pragma unroll
            for (int i = 0; i < 4; i++)
                a[i] = *(const short8*)&lds4[((wm * 4 + i) * 2 + ki) * 64 + lsw];
#pragma unroll
            for (int j = 0; j < 4; j++)
                bfr[j] = *(const short8*)&lds4[1024 + ((wn * 4 + j) * 2 + ki) * 64 + lsw];
#pragma unroll
            for (int i = 0; i < 4; i++)
#pragma unroll
                for (int j = 0; j < 4; j++)
                    acc[i][j] = __builtin_amdgcn_mfma_f32_16x16x32_bf16(
                        a[i], bfr[j], acc[i][j], 0, 0, 0);
        }
    }

    int quad = lane >> 4, col0 = lane & 15;
#pragma unroll
    for (int i = 0; i < 4; i++)
#pragma unroll
        for (int j = 0; j < 4; j++)
#pragma unroll
            for (int r = 0; r < 4; r++) {
                int row = m0 + (wm * 4 + i) * 16 + quad * 4 + r;
                int cc2 = n0 + (wn * 4 + j) * 16 + col0;
                if (CBF16)
                    ((unsigned short*)Cg + (long)bz * sC)[(long)row * ldc + cc2] =
                        (unsigned short)bf1(acc[i][j][r]);
                else
                    ((float*)Cg + (long)bz * sC)[(long)row * ldc + cc2] = acc[i][j][r];
            }
}

extern "C" void kernel_launch(void* const* d_in, const int* in_sizes, int n_in,
                              void* d_out, int out_size, void* d_ws, size_t ws_size,
                              hipStream_t stream) {
    const float* crd      = (const float*)d_in[0];
    const float* rot      = (const float*)d_in[1];
    const float* rot_init = (const float*)d_in[2];
    const float* trans    = (const float*)d_in[3];

    float* out   = (float*)d_out;
    float* y     = out;                          // [64,384,384] hartley (fp32)
    float* yreal = out + (size_t)NB * DD * DD;   // [64,384,384] real image
    // Ybf16 staging lives in the y output region (18.9MB < 37.7MB): written
    // by splat, read by stage-1, overwritten by stage-2's final y write.
    unsigned short* Ybf = (unsigned short*)y;

    char* ws = (char*)d_ws;
    unsigned short* Bt1 = (unsigned short*)ws;              // [U;S]   768x384
    unsigned short* Bt2 = (unsigned short*)(ws + 589824);   // [U|-2S] 384x768
    char* Zb = ws + 1179648;                                // Z region (37.7MB)
    unsigned short* Z = (unsigned short*)Zb;                // 64x768x384 bf16 (Z^T)
    // Bucketing scratch aliases Z (all dead before stage-1 GEMM writes Z):
    int*    counts  = (int*)Zb;                             // 64*20094*4 = 5,144,064 B
    int*    offs    = (int*)(Zb + 5144064);                 // 64*20098*4 = 5,145,088 B
    float2* sorted  = (float2*)(Zb + 10289152);             // 4,194,304 B
    float2* posed   = (float2*)(Zb + 14483456);             // 4,194,304 B
    int*    chunktot= (int*)(Zb + 18677760);                // 256*4 = 1,024 B
    // ends at 18,678,784 < 37,748,736 (Z size)

    hipMemsetAsync(counts, 0, (size_t)NB * NBKT * 4, stream);

    count_atoms<<<(NB * NATOM) / 256, 256, 0, stream>>>(crd, rot, rot_init, trans,
                                                        counts, posed);
    scan_a<<<NB * NCH, 1024, 0, stream>>>(counts, offs, chunktot);
    scan_b<<<NB * NCH, 1024, 0, stream>>>(offs, chunktot);
    scatter_atoms<<<(NB * NATOM) / 256, 256, 0, stream>>>(posed, counts, offs, sorted);
    splat_mfma<<<dim3(3, 12, NB), 256, 0, stream>>>(sorted, offs, yreal, Ybf);

    gen_w<<<(DD * DD + 255) / 256, 256, 0, stream>>>(Bt1, Bt2);

    // Stage 1 (swapped): C'[v][k] = sum_m Bt1[v][m]*Y[k][m] = Z^T,
    // M=768, N=384, K=384; A=Bt1 shared, B=Ybf batched bf16, C bf16.
    // nx=3 (384/128), bpi=3*6=18, nwg=18*64=1152 (div by 8 -> swizzle ok).
    gemm_mfma<true, false><<<1152, 256, 0, stream>>>(
        Bt1, Ybf, (long)DD * DD, (void*)Z, (long)768 * DD, DD, DD, 3, 18);

    // Stage 2 (swapped, folded-B): y[j][i] = sum_k Bt2[j][k]*Zt[i][k],
    // M=N=384, K=768; A=Bt2 shared, B=C' via fold addressing, C=y f32 direct.
    // nx=3, bpi=3*3=9, nwg=9*64=576 (div by 8 -> swizzle ok).
    gemm_mfma<false, true><<<576, 256, 0, stream>>>(
        Bt2, Z, (long)768 * DD, (void*)y, (long)DD * DD, 768, DD, 3, 9);
}

// Round 15
// 251.880 us; speedup vs baseline: 1.1006x; 1.1006x over previous
//
#include <hip/hip_runtime.h>

#define DD 384
#define NB 64
#define NATOM 8192
#define RB 394              // row buckets: icy+5, icy in [-5,388]
#define CB 51               // col buckets: (icx+16)>>3, icx in [-5,388] -> [1,50]
#define NBKT (RB * CB)      // 20094
#define OFFSTRIDE (NBKT + 4)
#define NCH 4               // scan chunks per image
#define CHSZ 5120           // buckets per chunk (4*5120 = 20480 >= NBKT)

typedef short short8 __attribute__((ext_vector_type(8)));
typedef float f32x4 __attribute__((ext_vector_type(4)));
typedef unsigned u32x4 __attribute__((ext_vector_type(4)));

// float -> bf16 (RNE) as ushort
__device__ inline unsigned bf1(float a) {
    unsigned u = __float_as_uint(a);
    return (u + 0x7FFFu + ((u >> 16) & 1u)) >> 16;
}
__device__ inline unsigned bfpack(float a, float b) {
    return bf1(a) | (bf1(b) << 16);
}

// async global->LDS, 16B per lane; dest = lds base (wave-uniform) + lane*16.
__device__ inline void gload_lds16(const void* g, void* l) {
    __builtin_amdgcn_global_load_lds(
        (const __attribute__((address_space(1))) unsigned*)g,
        (__attribute__((address_space(3))) unsigned*)l, 16, 0, 0);
}

// Pose one atom -> (X, Y) in physical coords.
__device__ inline float2 pose_one(const float* __restrict__ crd,
                                  const float* __restrict__ rot,
                                  const float* __restrict__ rot_init,
                                  const float* __restrict__ trans, int idx) {
    int b = idx >> 13;
    const float* p = crd + (long)idx * 3;
    float x0 = p[0], y0 = p[1], z0 = p[2];
    float q0 = x0 * rot_init[0] + y0 * rot_init[3] + z0 * rot_init[6] + trans[0];
    float q1 = x0 * rot_init[1] + y0 * rot_init[4] + z0 * rot_init[7] + trans[1];
    float q2 = x0 * rot_init[2] + y0 * rot_init[5] + z0 * rot_init[8] + trans[2];
    const float* R = rot + b * 9;
    float2 o;
    o.x = q0 * R[0] + q1 * R[1] + q2 * R[2];
    o.y = q0 * R[3] + q1 * R[4] + q2 * R[5];
    return o;
}

// ---------------------------------------------------------------------------
// Bucketing (R13 structure, verified 254us): count (+ pose cache) ->
// two-kernel parallel scan -> scatter. Unchanged.
// ---------------------------------------------------------------------------
__global__ void count_atoms(const float* __restrict__ crd,
                            const float* __restrict__ rot,
                            const float* __restrict__ rot_init,
                            const float* __restrict__ trans,
                            int* __restrict__ counts,
                            float2* __restrict__ posed) {
    int idx = blockIdx.x * 256 + threadIdx.x;
    float2 v = pose_one(crd, rot, rot_init, trans, idx);
    posed[idx] = v;
    int icx = (int)rintf(v.x + 192.0f);
    int icy = (int)rintf(v.y + 192.0f);
    if (icx < -5 || icx > 388 || icy < -5 || icy > 388) return;
    int bi = (icy + 5) * CB + ((icx + 16) >> 3);
    atomicAdd(&counts[(idx >> 13) * NBKT + bi], 1);
}

// scan_a: one block per (image, chunk); local exclusive scan of 5120 buckets
// (5 coalesced 1024-tiles), zeroes cnt (scatter cursors), emits chunk total.
__global__ __launch_bounds__(1024) void scan_a(int* __restrict__ counts,
                                               int* __restrict__ offs,
                                               int* __restrict__ chunktot) {
    int bc = blockIdx.x;                 // image*NCH + chunk
    int b = bc >> 2, ch = bc & 3;
    int base = ch * CHSZ;
    int t = threadIdx.x, lane = t & 63, wid = t >> 6;
    int* cnt = counts + b * NBKT;
    int* off = offs + b * OFFSTRIDE;
    __shared__ int wsum[16];
    __shared__ int carrySm;
    if (t == 0) carrySm = 0;
    __syncthreads();
    for (int tile = 0; tile < 5; ++tile) {
        int k = base + tile * 1024 + t;
        int v = (k < NBKT) ? cnt[k] : 0;  // coalesced
        int incl = v;
#pragma unroll
        for (int d = 1; d < 64; d <<= 1) {
            int u = __shfl_up(incl, d);
            if (lane >= d) incl += u;
        }
        if (lane == 63) wsum[wid] = incl;
        __syncthreads();
        if (wid == 0) {
            int s = (lane < 16) ? wsum[lane] : 0;
            int si = s;
#pragma unroll
            for (int d = 1; d < 16; d <<= 1) {
                int u = __shfl_up(si, d);
                if (lane >= d) si += u;
            }
            if (lane < 16) wsum[lane] = si - s;  // exclusive
        }
        __syncthreads();
        int excl = incl - v + wsum[wid] + carrySm;
        if (k < NBKT) {
            off[k] = excl;               // chunk-local exclusive scan
            cnt[k] = 0;                  // reuse as scatter cursor
        }
        __syncthreads();                 // reads of carrySm done before bump
        if (t == 1023) carrySm = excl + v;  // = carry_in + tile total
        __syncthreads();
    }
    if (t == 0) chunktot[bc] = carrySm;  // chunk total
}

// scan_b: one block per (image, chunk); adds the sum of preceding chunks'
// totals to this chunk's entries. Chunk-0 blocks write off[NBKT] = total.
__global__ __launch_bounds__(1024) void scan_b(int* __restrict__ offs,
                                               const int* __restrict__ chunktot) {
    int bc = blockIdx.x;
    int b = bc >> 2, ch = bc & 3;
    const int* ct = chunktot + b * NCH;
    int* off = offs + b * OFFSTRIDE;
    int t = threadIdx.x;
    if (ch == 0) {
        if (t == 0) off[NBKT] = ct[0] + ct[1] + ct[2] + ct[3];
        return;
    }
    int basev = 0;
    for (int i = 0; i < ch; i++) basev += ct[i];
    int k0 = ch * CHSZ;
    for (int tile = 0; tile < 5; ++tile) {
        int k = k0 + tile * 1024 + t;
        if (k < NBKT) off[k] += basev;   // coalesced RMW
    }
}

__global__ void scatter_atoms(const float2* __restrict__ posed,
                              int* __restrict__ cursors,
                              const int* __restrict__ offs,
                              float2* __restrict__ sorted) {
    int idx = blockIdx.x * 256 + threadIdx.x;
    float2 v = posed[idx];               // coalesced 8B re-read (same bits)
    int icx = (int)rintf(v.x + 192.0f);
    int icy = (int)rintf(v.y + 192.0f);
    if (icx < -5 || icx > 388 || icy < -5 || icy > 388) return;
    int b = idx >> 13;
    int bi = (icy + 5) * CB + ((icx + 16) >> 3);
    int pos = offs[b * OFFSTRIDE + bi] + atomicAdd(&cursors[b * NBKT + bi], 1);
    sorted[(long)b * NATOM + pos] = v;
}

// ---------------------------------------------------------------------------
// MFMA splat -- EXACT R13 version (verified 57us/dispatch, total 254us).
// R14's 32x32-per-wave amortization regressed (occupancy 43->16%, central-
// tile load imbalance): this kernel sits at a work-efficiency/occupancy
// local optimum -- do not re-tile. Gaussian separability: per 16x16 tile
// IMG = sum_a ey_a (x) ex_a = E_y^T*E_x, a GEMM with K=atoms; 32 atoms per
// mfma_f32_16x16x32_bf16. Epilogue writes f32 Y + bf16 copy for stage-1 B.
// ---------------------------------------------------------------------------
#define LCAP 512
#define LSZ  544   // LCAP + 32 pad slots

__global__ __launch_bounds__(256) void splat_mfma(const float2* __restrict__ sorted,
                                                  const int* __restrict__ offs,
                                                  float* __restrict__ img,
                                                  unsigned short* __restrict__ img_bf) {
    __shared__ __align__(16) float2 list[4][LSZ];
    int b = blockIdx.z;
    int wv = __builtin_amdgcn_readfirstlane((int)(threadIdx.x >> 6));
    int lane = threadIdx.x & 63;
    int tx = blockIdx.x * 4 + wv;      // 0..23
    int ty = blockIdx.y;               // 0..23
    int c0 = tx * 16, r0 = ty * 16;

    const int* off = offs + b * OFFSTRIDE;
    const float2* srt = sorted + (long)b * NATOM;

    int cb_lo = (c0 + 11) >> 3;          // loaded x-window [c0-8, c0+23]
    int cb_end = ((c0 + 36) >> 3) + 1;

    int cur = 0, iend = 0;
    if (lane < 26) {                     // one lane per row-bucket
        int rb = r0 + lane;              // icy = rb-5 in [r0-5, r0+20]
        cur = off[rb * CB + cb_lo];
        iend = off[rb * CB + cb_end];
    }

    f32x4 acc = {0.f, 0.f, 0.f, 0.f};
    int m = lane & 15;
    float rowf = (float)(r0 + m);        // a-side: pixel row (0..383)
    float colf = (float)(c0 + m);        // b-side: pixel col
    float py = rowf - 192.0f, px = colf - 192.0f;
    int g8 = (lane >> 4) << 3;           // k-slice base within chunk
    const float kneg = -0.32059868f;     // -(1/4.5)*log2(e)
    float2* wl = list[wv];

    for (int round = 0; round < 24; ++round) {
        int len = (lane < 26) ? (iend - cur) : 0;
        int incl = len;                  // exclusive scan via shfl_up
#pragma unroll
        for (int d = 1; d < 64; d <<= 1) {
            int t = __shfl_up(incl, d);
            if (lane >= d) incl += t;
        }
        int excl = incl - len;
        int totrem = __builtin_amdgcn_readfirstlane(__shfl(incl, 63));
        if (totrem == 0) break;
        int total = min(totrem, LCAP);
        int cnt = min(len, max(0, LCAP - excl));
        for (int j = 0; j < cnt; j++) wl[excl + j] = srt[cur + j];
        cur += cnt;
        int padn = (32 - (total & 31)) & 31;
        if (lane < padn) wl[total + lane] = (float2){3.0e5f, 3.0e5f};
        asm volatile("s_waitcnt lgkmcnt(0)" ::: "memory");  // wave-local LDS fence
        __builtin_amdgcn_sched_barrier(0);                  // no hoist past fence

        int nch = (total + 31) >> 5;
        for (int ch = 0; ch < nch; ch++) {
            const f32x4* qp = (const f32x4*)&wl[ch * 32 + g8];  // 2 atoms per read
            u32x4 au, bu;
#pragma unroll
            for (int p = 0; p < 4; p++) {
                f32x4 q = qp[p];         // (X0,Y0,X1,Y1); 16-lane broadcast
                // ey (row side)
                float d0 = py - q[1], d1 = py - q[3];
                float cy0 = rintf(q[1] + 192.0f), cy1 = rintf(q[3] + 192.0f);
                float e0 = (fabsf(rowf - cy0) <= 5.0f) ? exp2f(d0 * d0 * kneg) : 0.0f;
                float e1 = (fabsf(rowf - cy1) <= 5.0f) ? exp2f(d1 * d1 * kneg) : 0.0f;
                au[p] = bfpack(e0, e1);
                // ex (col side)
                float f0 = px - q[0], f1 = px - q[2];
                float cx0 = rintf(q[0] + 192.0f), cx1 = rintf(q[2] + 192.0f);
                float g0 = (fabsf(colf - cx0) <= 5.0f) ? exp2f(f0 * f0 * kneg) : 0.0f;
                float g1 = (fabsf(colf - cx1) <= 5.0f) ? exp2f(f1 * f1 * kneg) : 0.0f;
                bu[p] = bfpack(g0, g1);
            }
            short8 af = __builtin_bit_cast(short8, au);
            short8 bf = __builtin_bit_cast(short8, bu);
            acc = __builtin_amdgcn_mfma_f32_16x16x32_bf16(af, bf, acc, 0, 0, 0);
        }
        if (totrem <= LCAP) break;       // everything consumed this round
    }

    // C layout: col = lane&15, row = (lane>>4)*4 + r  (same as gemm_mfma)
    int col = c0 + m;
    int rbase = r0 + (lane >> 4) * 4;
#pragma unroll
    for (int r = 0; r < 4; r++) {
        long o = ((long)b * DD + rbase + r) * DD + col;
        img[o] = acc[r];
        img_bf[o] = (unsigned short)bf1(acc[r]);
    }
}

// ---------------------------------------------------------------------------
// DFT-derived weights (bf16): Bt1 = [U; S] (768x384), Bt2 = [U|-2S] (384x768).
// y = U*Y*U - 2*S*Y*S == Re(f)-Im(f) of double-fftshifted FFT2.
// ---------------------------------------------------------------------------
__global__ void gen_w(unsigned short* __restrict__ Bt1,
                      unsigned short* __restrict__ Bt2) {
    int idx = blockIdx.x * 256 + threadIdx.x;
    if (idx >= DD * DD) return;
    int i = idx / DD, j = idx % DD;
    int t = (i - 192) * (j - 192);
    int r = t % DD;
    if (r < 0) r += DD;
    float th = (float)r * (6.28318530717958647692f / (float)DD);
    float s = sinf(th), c = cosf(th);
    Bt1[i * DD + j] = (unsigned short)bf1(c + s);
    Bt1[(DD + i) * DD + j] = (unsigned short)bf1(s);
    Bt2[i * 768 + j] = (unsigned short)bf1(c + s);
    Bt2[i * 768 + 384 + j] = (unsigned short)bf1(-2.0f * s);
}

// ---------------------------------------------------------------------------
// bf16 MFMA GEMM: C[row][col] = sum_k A[row][k] * B[col][k].
// A is the SHARED bf16 weight matrix (row stride K). B is BATCHED (stride sB).
// 1D grid + bijective XCD swizzle (R7: FETCH 117->27MB).
// R15: staging via global_load_lds width=16 (compiler never auto-emits it;
// m97: +67% on staging-bound GEMM). LDS dest must be wave-uniform+lane*16
// => linear-in-c layout (slot c = row c>>3, kchunk (c&7)<<3). Linear layout
// would make fragment reads (row-stride 128B) 16-way bank-conflicted, so:
// XOR swizzle BOTH sides via pre-swizzled GLOBAL source (m173 pattern) --
// lane at phys slot c fetches logical c ^ ((c>>3)&7) (involution; permutes
// within one 128B row-chunk so global coalescing unchanged), and reads use
// slot (ki*4 + (lane>>4)) ^ (lane&7) -> 2-way conflicts (free).
// BFOLD: B is the folded view of stage-1's C' (768x384 bf16):
// B[i][k] = k<384 ? C'[i][k] : C'[384+i][k-384] (16B runs stay in one half).
// ---------------------------------------------------------------------------
template <bool CBF16, bool BFOLD>
__global__ __launch_bounds__(256) void gemm_mfma(const unsigned short* __restrict__ Ag,
                                                 const unsigned short* __restrict__ Bg,
                                                 long sB,
                                                 void* __restrict__ Cg, long sC,
                                                 int K, int ldc, int nx, int bpi) {
    __shared__ uint4 lds4[2048];  // A: [0,1024), B: [1024,2048)

    int cpx = gridDim.x >> 3;                 // blocks per XCD chunk
    int wg = blockIdx.x;
    int lin = (wg & 7) * cpx + (wg >> 3);     // bijective XCD swizzle
    int bz = lin / bpi;
    int rr = lin - bz * bpi;
    int m0 = (rr / nx) * 128, n0 = (rr % nx) * 128;
    int tid = threadIdx.x;
    int lane = tid & 63, w = tid >> 6;
    int wm = w >> 1, wn = w & 1;

    f32x4 acc[4][4];
#pragma unroll
    for (int i = 0; i < 4; i++)
#pragma unroll
        for (int j = 0; j < 4; j++) acc[i][j] = (f32x4){0.f, 0.f, 0.f, 0.f};

    const unsigned short* Bh = Bg + (long)bz * sB;

    for (int k0 = 0; k0 < K; k0 += 64) {
        __syncthreads();
#pragma unroll
        for (int cc = 0; cc < 4; cc++) {
            int cph = cc * 256 + tid;            // physical LDS slot
            int clg = cph ^ ((cph >> 3) & 7);    // logical slot (involution)
            int mm = clg >> 3, kc = (clg & 7) << 3;
            const unsigned short* gA = Ag + (long)(m0 + mm) * K + k0 + kc;
            const unsigned short* gB;
            if (BFOLD) {
                int kk = k0 + kc;                // 16B run within one 384-half
                gB = Bh + ((kk >= 384) ? ((long)(384 + n0 + mm) * 384 + (kk - 384))
                                       : ((long)(n0 + mm) * 384 + kk));
            } else {
                gB = Bh + (long)(n0 + mm) * K + k0 + kc;
            }
            gload_lds16(gA, &lds4[cc * 256 + w * 64]);         // + lane*16B
            gload_lds16(gB, &lds4[1024 + cc * 256 + w * 64]);  // + lane*16B
        }
        __syncthreads();   // compiler drains vmcnt before the barrier
#pragma unroll
        for (int ki = 0; ki < 2; ki++) {
            int slot = (ki * 4 + (lane >> 4)) ^ (lane & 7);  // read-side swizzle
            short8 a[4], bfr[4];
#pragma unroll
            for (int i = 0; i < 4; i++) {
                int mr = (wm * 4 + i) * 16 + (lane & 15);
                a[i] = *(const short8*)&lds4[mr * 8 + slot];
            }
#pragma unroll
            for (int j = 0; j < 4; j++) {
                int nr = (wn * 4 + j) * 16 + (lane & 15);
                bfr[j] = *(const short8*)&lds4[1024 + nr * 8 + slot];
            }
#pragma unroll
            for (int i = 0; i < 4; i++)
#pragma unroll
                for (int j = 0; j < 4; j++)
                    acc[i][j] = __builtin_amdgcn_mfma_f32_16x16x32_bf16(
                        a[i], bfr[j], acc[i][j], 0, 0, 0);
        }
    }

    int quad = lane >> 4, col0 = lane & 15;
#pragma unroll
    for (int i = 0; i < 4; i++)
#pragma unroll
        for (int j = 0; j < 4; j++)
#pragma unroll
            for (int r = 0; r < 4; r++) {
                int row = m0 + (wm * 4 + i) * 16 + quad * 4 + r;
                int cc2 = n0 + (wn * 4 + j) * 16 + col0;
                if (CBF16)
                    ((unsigned short*)Cg + (long)bz * sC)[(long)row * ldc + cc2] =
                        (unsigned short)bf1(acc[i][j][r]);
                else
                    ((float*)Cg + (long)bz * sC)[(long)row * ldc + cc2] = acc[i][j][r];
            }
}

extern "C" void kernel_launch(void* const* d_in, const int* in_sizes, int n_in,
                              void* d_out, int out_size, void* d_ws, size_t ws_size,
                              hipStream_t stream) {
    const float* crd      = (const float*)d_in[0];
    const float* rot      = (const float*)d_in[1];
    const float* rot_init = (const float*)d_in[2];
    const float* trans    = (const float*)d_in[3];

    float* out   = (float*)d_out;
    float* y     = out;                          // [64,384,384] hartley (fp32)
    float* yreal = out + (size_t)NB * DD * DD;   // [64,384,384] real image
    // Ybf16 staging lives in the y output region (18.9MB < 37.7MB): written
    // by splat, read by stage-1, overwritten by stage-2's final y write.
    unsigned short* Ybf = (unsigned short*)y;

    char* ws = (char*)d_ws;
    unsigned short* Bt1 = (unsigned short*)ws;              // [U;S]   768x384
    unsigned short* Bt2 = (unsigned short*)(ws + 589824);   // [U|-2S] 384x768
    char* Zb = ws + 1179648;                                // Z region (37.7MB)
    unsigned short* Z = (unsigned short*)Zb;                // 64x768x384 bf16 (Z^T)
    // Bucketing scratch aliases Z (all dead before stage-1 GEMM writes Z):
    int*    counts  = (int*)Zb;                             // 64*20094*4 = 5,144,064 B
    int*    offs    = (int*)(Zb + 5144064);                 // 64*20098*4 = 5,145,088 B
    float2* sorted  = (float2*)(Zb + 10289152);             // 4,194,304 B
    float2* posed   = (float2*)(Zb + 14483456);             // 4,194,304 B
    int*    chunktot= (int*)(Zb + 18677760);                // 256*4 = 1,024 B
    // ends at 18,678,784 < 37,748,736 (Z size)

    hipMemsetAsync(counts, 0, (size_t)NB * NBKT * 4, stream);

    count_atoms<<<(NB * NATOM) / 256, 256, 0, stream>>>(crd, rot, rot_init, trans,
                                                        counts, posed);
    scan_a<<<NB * NCH, 1024, 0, stream>>>(counts, offs, chunktot);
    scan_b<<<NB * NCH, 1024, 0, stream>>>(offs, chunktot);
    scatter_atoms<<<(NB * NATOM) / 256, 256, 0, stream>>>(posed, counts, offs, sorted);
    splat_mfma<<<dim3(6, 24, NB), 256, 0, stream>>>(sorted, offs, yreal, Ybf);

    gen_w<<<(DD * DD + 255) / 256, 256, 0, stream>>>(Bt1, Bt2);

    // Stage 1 (swapped): C'[v][k] = sum_m Bt1[v][m]*Y[k][m] = Z^T,
    // M=768, N=384, K=384; A=Bt1 shared, B=Ybf batched bf16, C bf16.
    // nx=3 (384/128), bpi=3*6=18, nwg=18*64=1152 (div by 8 -> swizzle ok).
    gemm_mfma<true, false><<<1152, 256, 0, stream>>>(
        Bt1, Ybf, (long)DD * DD, (void*)Z, (long)768 * DD, DD, DD, 3, 18);

    // Stage 2 (swapped, folded-B): y[j][i] = sum_k Bt2[j][k]*Zt[i][k],
    // M=N=384, K=768; A=Bt2 shared, B=C' via fold addressing, C=y f32 direct.
    // nx=3, bpi=3*3=9, nwg=9*64=576 (div by 8 -> swizzle ok).
    gemm_mfma<false, true><<<576, 256, 0, stream>>>(
        Bt2, Z, (long)768 * DD, (void*)y, (long)DD * DD, 768, DD, 3, 9);
}